// Round 2
// baseline (3208.873 us; speedup 1.0000x reference)
//
#include <hip/hip_runtime.h>
#include <hip/hip_bf16.h>

typedef unsigned short u16;

#define Bb 4
#define Ss 2048
#define Dd 1024
#define Rr 512
#define Hh 8
#define NCn 8
#define NEn 8
#define DHd 64
#define Mm 8192   // B*S

__device__ __forceinline__ float bf2f(u16 u){
    union { unsigned int i; float f; } v; v.i = ((unsigned int)u)<<16; return v.f;
}

// dtype-adaptive 4-element load: idx must be a multiple of 4 elements
__device__ __forceinline__ float4 ld4(const void* p, size_t idx, bool isbf){
    if (isbf){
        ushort4 v = *(const ushort4*)((const u16*)p + idx);
        return make_float4(bf2f(v.x), bf2f(v.y), bf2f(v.z), bf2f(v.w));
    } else {
        return *(const float4*)((const float*)p + idx);
    }
}

// ---------------- Kernel 0: input dtype detector ----------------
// bf16-packed data: low 16 bits of each 32-bit word are a bf16 of ~N(0,1)
// (exponent field in [100,140] w.p. ~1). True f32: low 16 bits are uniform
// mantissa bits (hit window ~16%). 64 samples, threshold 40.
__global__ void k_detect(const unsigned int* __restrict__ xw, int* __restrict__ flag){
    const unsigned int w = xw[threadIdx.x];
    const unsigned int e = (w >> 7) & 0xFF;
    const bool bflike = (e >= 100) && (e <= 140) && ((w & 0xFFFF) != 0);
    unsigned long long b = __ballot(bflike);
    if (threadIdx.x == 0) *flag = (__popcll(b) >= 40) ? 1 : 0;
}

// ---------------- Kernel 1: q/k/v router softmax weights [M,8] each ----------------
__global__ __launch_bounds__(64) void k_router_qkv(
    const void* __restrict__ x, const void* __restrict__ wrq,
    const void* __restrict__ wrk, const void* __restrict__ wrv,
    const int* __restrict__ flag,
    float* __restrict__ wq, float* __restrict__ wk, float* __restrict__ wv)
{
    const bool isbf = (*flag != 0);
    const int m = blockIdx.x;
    const int lane = threadIdx.x;
    float aq[8], ak[8], av[8];
#pragma unroll
    for (int r=0;r<8;r++){ aq[r]=0.f; ak[r]=0.f; av[r]=0.f; }
#pragma unroll
    for (int i=0;i<4;i++){
        const size_t d0 = i*256 + lane*4;
        float4 xv = ld4(x, (size_t)m*Dd + d0, isbf);
#pragma unroll
        for (int r=0;r<8;r++){
            float4 q4 = ld4(wrq, (size_t)r*Dd + d0, isbf);
            aq[r] += xv.x*q4.x + xv.y*q4.y + xv.z*q4.z + xv.w*q4.w;
            float4 k4 = ld4(wrk, (size_t)r*Dd + d0, isbf);
            ak[r] += xv.x*k4.x + xv.y*k4.y + xv.z*k4.z + xv.w*k4.w;
            float4 v4 = ld4(wrv, (size_t)r*Dd + d0, isbf);
            av[r] += xv.x*v4.x + xv.y*v4.y + xv.z*v4.z + xv.w*v4.w;
        }
    }
#pragma unroll
    for (int r=0;r<8;r++){
#pragma unroll
        for (int off=32;off>=1;off>>=1){
            aq[r]+=__shfl_xor(aq[r],off);
            ak[r]+=__shfl_xor(ak[r],off);
            av[r]+=__shfl_xor(av[r],off);
        }
    }
    float mq=aq[0], mk=ak[0], mv=av[0];
#pragma unroll
    for (int r=1;r<8;r++){ mq=fmaxf(mq,aq[r]); mk=fmaxf(mk,ak[r]); mv=fmaxf(mv,av[r]); }
    float eq[8], ek[8], ev[8], sq=0.f, sk=0.f, sv=0.f;
#pragma unroll
    for (int r=0;r<8;r++){
        eq[r]=expf(aq[r]-mq); sq+=eq[r];
        ek[r]=expf(ak[r]-mk); sk+=ek[r];
        ev[r]=expf(av[r]-mv); sv+=ev[r];
    }
    if (lane < 8)        wq[m*8+lane]    = eq[lane]/sq;
    else if (lane < 16)  wk[m*8+lane-8]  = ek[lane-8]/sk;
    else if (lane < 24)  wv[m*8+lane-16] = ev[lane-16]/sv;
}

// ---------------- Kernel 2: fused compress GEMM -> q,k,v [M,R] fp32 ----------------
#define BK 16
__global__ __launch_bounds__(256) void k_compress(
    const void* __restrict__ x, const void* __restrict__ cn,
    const int* __restrict__ flag,
    const float* __restrict__ wq, const float* __restrict__ wk, const float* __restrict__ wv,
    float* __restrict__ qb, float* __restrict__ kb, float* __restrict__ vb)
{
    __shared__ float As[BK][64+4];   // [k][m]
    __shared__ float Bs[BK][64+4];   // [k][r]
    const bool isbf = (*flag != 0);
    const int tid = threadIdx.x;
    const int ty = tid>>4, tx = tid&15;
    const int m0 = blockIdx.y*64, r0 = blockIdx.x*64;
    const int arow = tid>>2, aq_ = tid&3;
    const int bkr = tid>>4, bq = tid&15;
    float accq[4][4]={}, acck[4][4]={}, accv[4][4]={};
    for (int n=0;n<NCn;n++){
        float accn[4][4]={};
        const size_t bn = (size_t)n*Dd*Rr;
        for (int kt=0;kt<Dd/BK;kt++){
            __syncthreads();
            {
                float4 v = ld4(x, (size_t)(m0+arow)*Dd + kt*BK + aq_*4, isbf);
                As[aq_*4+0][arow]=v.x; As[aq_*4+1][arow]=v.y;
                As[aq_*4+2][arow]=v.z; As[aq_*4+3][arow]=v.w;
            }
            {
                float4 f = ld4(cn, bn + (size_t)(kt*BK+bkr)*Rr + r0 + bq*4, isbf);
                *(float4*)&Bs[bkr][bq*4] = f;
            }
            __syncthreads();
#pragma unroll
            for (int kk=0;kk<BK;kk++){
                float4 a4 = *(float4*)&As[kk][ty*4];
                float4 b4 = *(float4*)&Bs[kk][tx*4];
                float a[4]={a4.x,a4.y,a4.z,a4.w};
                float b[4]={b4.x,b4.y,b4.z,b4.w};
#pragma unroll
                for (int i=0;i<4;i++)
#pragma unroll
                    for (int j=0;j<4;j++) accn[i][j] += a[i]*b[j];
            }
        }
#pragma unroll
        for (int i=0;i<4;i++){
            const int mg = m0 + ty*4 + i;
            const float wqv = wq[mg*8+n], wkv = wk[mg*8+n], wvv = wv[mg*8+n];
#pragma unroll
            for (int j=0;j<4;j++){
                accq[i][j] += wqv*accn[i][j];
                acck[i][j] += wkv*accn[i][j];
                accv[i][j] += wvv*accn[i][j];
            }
        }
    }
#pragma unroll
    for (int i=0;i<4;i++){
        const int mg = m0 + ty*4 + i;
        *(float4*)&qb[(size_t)mg*Rr + r0 + tx*4] = make_float4(accq[i][0],accq[i][1],accq[i][2],accq[i][3]);
        *(float4*)&kb[(size_t)mg*Rr + r0 + tx*4] = make_float4(acck[i][0],acck[i][1],acck[i][2],acck[i][3]);
        *(float4*)&vb[(size_t)mg*Rr + r0 + tx*4] = make_float4(accv[i][0],accv[i][1],accv[i][2],accv[i][3]);
    }
}

// ---------------- Kernel 3: causal flash attention (fp32, 64x64 tiles) ----------------
// LDS: Qt + Vs + (K-tile unioned with S-tile) = 3*17408 + 768 = 52992 B (< 64 KiB)
__global__ __launch_bounds__(256) void k_attn(
    const float* __restrict__ qb, const float* __restrict__ kb, const float* __restrict__ vb,
    float* __restrict__ ab)
{
    __shared__ float Qt[64][68];    // [d][qrow]
    __shared__ float KSt[64][68];   // phase A: K^T [d][key]; phase B: P [key][qrow]
    __shared__ float Vs[64][68];    // [key][d]
    __shared__ float m_l[64], l_l[64], al_l[64];
    const int tid = threadIdx.x;
    const int qt = blockIdx.x, bh = blockIdx.y;
    const int b = bh>>3, h = bh&7;
    const int ty = tid>>4, tx = tid&15;
    const int lrow = tid>>2, lq = tid&3;
    const float* qbase = qb + (size_t)(b*Ss)*Rr + h*DHd;
    const float* kbase = kb + (size_t)(b*Ss)*Rr + h*DHd;
    const float* vbase = vb + (size_t)(b*Ss)*Rr + h*DHd;
#pragma unroll
    for (int jj=lq; jj<16; jj+=4){
        float4 v = *(const float4*)(qbase + (size_t)(qt*64+lrow)*Rr + jj*4);
        Qt[jj*4+0][lrow]=v.x; Qt[jj*4+1][lrow]=v.y; Qt[jj*4+2][lrow]=v.z; Qt[jj*4+3][lrow]=v.w;
    }
    if (tid < 64){ m_l[tid] = -1e30f; l_l[tid] = 0.f; }
    float o[4][4]={};
    for (int kt=0; kt<=qt; kt++){
        __syncthreads();   // previous iteration's readers of KSt/Vs are done
#pragma unroll
        for (int jj=lq; jj<16; jj+=4){
            float4 kv = *(const float4*)(kbase + (size_t)(kt*64+lrow)*Rr + jj*4);
            KSt[jj*4+0][lrow]=kv.x; KSt[jj*4+1][lrow]=kv.y; KSt[jj*4+2][lrow]=kv.z; KSt[jj*4+3][lrow]=kv.w;
            float4 vv = *(const float4*)(vbase + (size_t)(kt*64+lrow)*Rr + jj*4);
            *(float4*)&Vs[lrow][jj*4] = vv;
        }
        __syncthreads();
        // S = Q @ K^T (registers only)
        float s[4][4]={};
#pragma unroll
        for (int d=0; d<64; d++){
            float4 q4 = *(float4*)&Qt[d][ty*4];
            float4 k4 = *(float4*)&KSt[d][tx*4];
            float qv[4]={q4.x,q4.y,q4.z,q4.w};
            float kv[4]={k4.x,k4.y,k4.z,k4.w};
#pragma unroll
            for (int i=0;i<4;i++)
#pragma unroll
                for (int j=0;j<4;j++) s[i][j] += qv[i]*kv[j];
        }
        __syncthreads();   // everyone done READING KSt as K^T; safe to overwrite as S
#pragma unroll
        for (int i=0;i<4;i++){
            const int qg = qt*64 + ty*4 + i;
#pragma unroll
            for (int j=0;j<4;j++){
                const int kg = kt*64 + tx*4 + j;
                float sv = s[i][j]*0.125f;           // 1/sqrt(64)
                if (kg > qg) sv = -1e30f;            // causal mask
                KSt[tx*4+j][ty*4+i] = sv;            // [key][qrow]
            }
        }
        __syncthreads();
        // online softmax (one thread per query row)
        if (tid < 64){
            const int r = tid;
            const float mo = m_l[r];
            float mt = mo;
#pragma unroll 8
            for (int j=0;j<64;j++) mt = fmaxf(mt, KSt[j][r]);
            const float al = expf(mo - mt);
            float sum = 0.f;
#pragma unroll 8
            for (int j=0;j<64;j++){
                float p = expf(KSt[j][r] - mt);
                KSt[j][r] = p; sum += p;
            }
            l_l[r] = l_l[r]*al + sum;
            m_l[r] = mt;
            al_l[r] = al;
        }
        __syncthreads();
        float alr[4];
#pragma unroll
        for (int i=0;i<4;i++) alr[i] = al_l[ty*4+i];
#pragma unroll
        for (int i=0;i<4;i++)
#pragma unroll
            for (int j=0;j<4;j++) o[i][j] *= alr[i];
#pragma unroll
        for (int jk=0;jk<64;jk++){
            float4 p4 = *(float4*)&KSt[jk][ty*4];
            float4 v4 = *(float4*)&Vs[jk][tx*4];
            float pv[4]={p4.x,p4.y,p4.z,p4.w};
            float vv[4]={v4.x,v4.y,v4.z,v4.w};
#pragma unroll
            for (int i=0;i<4;i++)
#pragma unroll
                for (int j=0;j<4;j++) o[i][j] += pv[i]*vv[j];
        }
    }
    float* abase = ab + (size_t)(b*Ss)*Rr + h*DHd;
#pragma unroll
    for (int i=0;i<4;i++){
        const int qg = qt*64 + ty*4 + i;
        const float inv = 1.f / l_l[ty*4+i];
        *(float4*)&abase[(size_t)qg*Rr + tx*4] =
            make_float4(o[i][0]*inv, o[i][1]*inv, o[i][2]*inv, o[i][3]*inv);
    }
}

// ---------------- Kernel 4: output router softmax weights [M,8] ----------------
__global__ __launch_bounds__(64) void k_router_o(
    const float* __restrict__ ab, const void* __restrict__ wro,
    const int* __restrict__ flag, float* __restrict__ wo)
{
    const bool isbf = (*flag != 0);
    const int m = blockIdx.x, lane = threadIdx.x;
    float a[8];
#pragma unroll
    for (int r=0;r<8;r++) a[r]=0.f;
#pragma unroll
    for (int i=0;i<2;i++){
        const size_t d0 = i*256 + lane*4;
        float4 av = *(const float4*)(ab + (size_t)m*Rr + d0);
#pragma unroll
        for (int r=0;r<8;r++){
            float4 w4 = ld4(wro, (size_t)r*Rr + d0, isbf);
            a[r] += av.x*w4.x + av.y*w4.y + av.z*w4.z + av.w*w4.w;
        }
    }
#pragma unroll
    for (int r=0;r<8;r++)
#pragma unroll
        for (int off=32;off>=1;off>>=1) a[r]+=__shfl_xor(a[r],off);
    float mx=a[0];
#pragma unroll
    for (int r=1;r<8;r++) mx=fmaxf(mx,a[r]);
    float e[8], s=0.f;
#pragma unroll
    for (int r=0;r<8;r++){ e[r]=expf(a[r]-mx); s+=e[r]; }
    if (lane < 8) wo[m*8+lane] = e[lane]/s;
}

// ---------------- Kernel 5: fused expand GEMM -> out [M,D] ----------------
__global__ __launch_bounds__(256) void k_expand(
    const float* __restrict__ ab, const void* __restrict__ en,
    const int* __restrict__ flag, const float* __restrict__ wo,
    void* __restrict__ outv)
{
    __shared__ float As[BK][64+4];
    __shared__ float Bs[BK][64+4];
    const bool isbf = (*flag != 0);
    const int tid = threadIdx.x;
    const int ty = tid>>4, tx = tid&15;
    const int m0 = blockIdx.y*64, d0 = blockIdx.x*64;
    const int arow = tid>>2, aq_ = tid&3;
    const int bkr = tid>>4, bq = tid&15;
    float acco[4][4]={};
    for (int n=0;n<NEn;n++){
        float accn[4][4]={};
        const size_t bn = (size_t)n*Rr*Dd;
        for (int kt=0;kt<Rr/BK;kt++){
            __syncthreads();
            {
                float4 av = *(const float4*)(ab + (size_t)(m0+arow)*Rr + kt*BK + aq_*4);
                As[aq_*4+0][arow]=av.x; As[aq_*4+1][arow]=av.y;
                As[aq_*4+2][arow]=av.z; As[aq_*4+3][arow]=av.w;
            }
            {
                float4 f = ld4(en, bn + (size_t)(kt*BK+bkr)*Dd + d0 + bq*4, isbf);
                *(float4*)&Bs[bkr][bq*4] = f;
            }
            __syncthreads();
#pragma unroll
            for (int kk=0;kk<BK;kk++){
                float4 a4 = *(float4*)&As[kk][ty*4];
                float4 b4 = *(float4*)&Bs[kk][tx*4];
                float a[4]={a4.x,a4.y,a4.z,a4.w};
                float b[4]={b4.x,b4.y,b4.z,b4.w};
#pragma unroll
                for (int i=0;i<4;i++)
#pragma unroll
                    for (int j=0;j<4;j++) accn[i][j] += a[i]*b[j];
            }
        }
#pragma unroll
        for (int i=0;i<4;i++){
            const float wov = wo[(size_t)(m0+ty*4+i)*8+n];
#pragma unroll
            for (int j=0;j<4;j++) acco[i][j] += wov*accn[i][j];
        }
    }
#pragma unroll
    for (int i=0;i<4;i++){
        const size_t mg = m0 + ty*4 + i;
        if (isbf){
            __hip_bfloat16* ob = (__hip_bfloat16*)outv;
#pragma unroll
            for (int j=0;j<4;j++)
                ob[mg*Dd + d0 + tx*4 + j] = __float2bfloat16(acco[i][j]);
        } else {
            float* ob = (float*)outv;
            *(float4*)&ob[mg*Dd + d0 + tx*4] =
                make_float4(acco[i][0],acco[i][1],acco[i][2],acco[i][3]);
        }
    }
}

extern "C" void kernel_launch(void* const* d_in, const int* in_sizes, int n_in,
                              void* d_out, int out_size, void* d_ws, size_t ws_size,
                              hipStream_t stream) {
    (void)in_sizes; (void)n_in; (void)out_size; (void)ws_size;
    const void* x   = d_in[0];
    // d_in[1] = causal mask — deterministic, unused
    const void* cn  = d_in[2];
    const void* en  = d_in[3];
    const void* wrq = d_in[4];
    const void* wrk = d_in[5];
    const void* wrv = d_in[6];
    const void* wro = d_in[7];

    int*   flag = (int*)d_ws;
    float* ws   = (float*)d_ws + 16;    // 64B-aligned region after flag
    float* wq = ws;                     // [M,8]
    float* wk = wq + Mm*8;
    float* wv = wk + Mm*8;
    float* wo = wv + Mm*8;
    float* qb = wo + Mm*8;              // [M,R]
    float* kb = qb + (size_t)Mm*Rr;
    float* vb = kb + (size_t)Mm*Rr;
    float* ab = vb + (size_t)Mm*Rr;     // attention output [M,R]

    k_detect<<<1, 64, 0, stream>>>((const unsigned int*)x, flag);
    k_router_qkv<<<Mm, 64, 0, stream>>>(x, wrq, wrk, wrv, flag, wq, wk, wv);
    k_compress<<<dim3(Rr/64, Mm/64), 256, 0, stream>>>(x, cn, flag, wq, wk, wv, qb, kb, vb);
    k_attn<<<dim3(Ss/64, Bb*Hh), 256, 0, stream>>>(qb, kb, vb, ab);
    k_router_o<<<Mm, 64, 0, stream>>>(ab, wro, flag, wo);
    k_expand<<<dim3(Dd/64, Mm/64), 256, 0, stream>>>(ab, en, flag, wo, d_out);
}

// Round 4
// 1245.730 us; speedup vs baseline: 2.5759x; 2.5759x over previous
//
#include <hip/hip_runtime.h>
#include <hip/hip_bf16.h>

typedef unsigned short u16;
typedef __attribute__((ext_vector_type(8))) short s8v;   // 8 bf16 (4 VGPRs) MFMA A/B frag
typedef __attribute__((ext_vector_type(4))) float f4v;   // MFMA C/D frag

#define Bb 4
#define Ss 2048
#define Dd 1024
#define Rr 512
#define Hh 8
#define DHd 64
#define Mm 8192   // B*S

__device__ __forceinline__ float bf2f(u16 u){
    union { unsigned int i; float f; } v; v.i = ((unsigned int)u)<<16; return v.f;
}
__device__ __forceinline__ u16 f2bf(float f){
    __hip_bfloat16 h = __float2bfloat16(f);
    return *(u16*)&h;
}
__device__ __forceinline__ void gld_lds16(const u16* g, u16* l){
    // async global->LDS, 16B/lane; LDS dest = (wave-uniform base) + lane*16
    __builtin_amdgcn_global_load_lds((const __attribute__((address_space(1))) unsigned int*)g,
                                     (__attribute__((address_space(3))) unsigned int*)l, 16, 0, 0);
}

// ---------------- fp32 -> bf16 bulk convert ----------------
__global__ __launch_bounds__(256) void k_f2b(
    const float* __restrict__ in, u16* __restrict__ out)
{
    const size_t i = (size_t)blockIdx.x*256 + threadIdx.x;
    float4 v = ((const float4*)in)[i];
    ushort4 o;
    o.x = f2bf(v.x); o.y = f2bf(v.y); o.z = f2bf(v.z); o.w = f2bf(v.w);
    ((ushort4*)out)[i] = o;
}

// ---------------- transpose + convert: src[n][A][B] f32 -> dst[n][B][A] bf16 ----------------
__global__ __launch_bounds__(256) void k_transpose_f2b(
    const float* __restrict__ src, u16* __restrict__ dst, int A, int B)
{
    __shared__ float t[64][65];
    const int a0 = blockIdx.x*64, b0 = blockIdx.y*64, n = blockIdx.z;
    const size_t sbase = (size_t)n*A*B;
    const int r = threadIdx.x>>4, c = threadIdx.x&15;
#pragma unroll
    for (int p=0;p<4;p++){
        const int ar = r + p*16;
        float4 v = *(const float4*)(src + sbase + (size_t)(a0+ar)*B + b0 + c*4);
        t[ar][c*4+0]=v.x; t[ar][c*4+1]=v.y; t[ar][c*4+2]=v.z; t[ar][c*4+3]=v.w;
    }
    __syncthreads();
#pragma unroll
    for (int p=0;p<4;p++){
        const int br = r + p*16;
        ushort4 o;
        o.x = f2bf(t[c*4+0][br]); o.y = f2bf(t[c*4+1][br]);
        o.z = f2bf(t[c*4+2][br]); o.w = f2bf(t[c*4+3][br]);
        *(ushort4*)(dst + sbase + (size_t)(b0+br)*A + a0 + c*4) = o;
    }
}

// ---------------- q/k/v router softmax weights [M,8] each (fp32 in) ----------------
__global__ __launch_bounds__(64) void k_router_qkv(
    const float* __restrict__ x, const float* __restrict__ wrq,
    const float* __restrict__ wrk, const float* __restrict__ wrv,
    float* __restrict__ wq, float* __restrict__ wk, float* __restrict__ wv)
{
    const int m = blockIdx.x, lane = threadIdx.x;
    float aq[8], ak[8], av[8];
#pragma unroll
    for (int r=0;r<8;r++){ aq[r]=0.f; ak[r]=0.f; av[r]=0.f; }
#pragma unroll
    for (int i=0;i<4;i++){
        const size_t d0 = i*256 + lane*4;
        float4 xv = *(const float4*)(x + (size_t)m*Dd + d0);
#pragma unroll
        for (int r=0;r<8;r++){
            float4 q4 = *(const float4*)(wrq + (size_t)r*Dd + d0);
            aq[r] += xv.x*q4.x + xv.y*q4.y + xv.z*q4.z + xv.w*q4.w;
            float4 k4 = *(const float4*)(wrk + (size_t)r*Dd + d0);
            ak[r] += xv.x*k4.x + xv.y*k4.y + xv.z*k4.z + xv.w*k4.w;
            float4 v4 = *(const float4*)(wrv + (size_t)r*Dd + d0);
            av[r] += xv.x*v4.x + xv.y*v4.y + xv.z*v4.z + xv.w*v4.w;
        }
    }
#pragma unroll
    for (int r=0;r<8;r++){
#pragma unroll
        for (int off=32;off>=1;off>>=1){
            aq[r]+=__shfl_xor(aq[r],off);
            ak[r]+=__shfl_xor(ak[r],off);
            av[r]+=__shfl_xor(av[r],off);
        }
    }
    float mq=aq[0], mk=ak[0], mv=av[0];
#pragma unroll
    for (int r=1;r<8;r++){ mq=fmaxf(mq,aq[r]); mk=fmaxf(mk,ak[r]); mv=fmaxf(mv,av[r]); }
    float eq[8], ek[8], ev[8], sq=0.f, sk=0.f, sv=0.f;
#pragma unroll
    for (int r=0;r<8;r++){
        eq[r]=expf(aq[r]-mq); sq+=eq[r];
        ek[r]=expf(ak[r]-mk); sk+=ek[r];
        ev[r]=expf(av[r]-mv); sv+=ev[r];
    }
    if (lane < 8)        wq[m*8+lane]    = eq[lane]/sq;
    else if (lane < 16)  wk[m*8+lane-8]  = ek[lane-8]/sk;
    else if (lane < 24)  wv[m*8+lane-16] = ev[lane-16]/sv;
}

// ---------------- compress: q,k,v [M,R] bf16 via MFMA ----------------
// block tile 128m x 64r; wave tile 64x32; n-outer, epilogue-weighted fp32 acc
__global__ __launch_bounds__(256) void k_compress_mfma(
    const u16* __restrict__ xb, const u16* __restrict__ cnT,
    const float* __restrict__ wq, const float* __restrict__ wk, const float* __restrict__ wv,
    u16* __restrict__ qb, u16* __restrict__ kb, u16* __restrict__ vb)
{
    __shared__ __align__(16) u16 As[128*32];   // [m][k32], 16B chunks XOR-swizzled by m&3
    __shared__ __align__(16) u16 Bs[64*32];    // [r][k32], swizzled by r&3
    __shared__ float wL[3][8][128];
    const int tid = threadIdx.x;
    const int lane = tid & 63, w = tid >> 6;
    const int m0 = blockIdx.y*128, r0 = blockIdx.x*64;
    for (int i = tid; i < 3*8*128; i += 256){
        const int t = i >> 10, rem = i & 1023, n = rem >> 7, ml = rem & 127;
        const float* wsrc = (t==0)? wq : (t==1)? wk : wv;
        wL[t][n][ml] = wsrc[(size_t)(m0+ml)*8 + n];
    }
    const int wm = (w&1)*64, wr = (w>>1)*32;
    const int swz = ((lane>>4) ^ (lane&3));
    int aoff[4], boff[2];
#pragma unroll
    for (int mt=0;mt<4;mt++) aoff[mt] = (wm + mt*16 + (lane&15))*64 + swz*16;  // bytes
#pragma unroll
    for (int rt=0;rt<2;rt++) boff[rt] = (wr + rt*16 + (lane&15))*64 + swz*16;
    const int srow = lane>>2, sq = lane&3;
    const int schunk = (sq ^ (srow&3))<<3;     // element offset of swizzled chunk
    f4v accq[4][2], acck[4][2], accv[4][2];
    const f4v fz = {0.f,0.f,0.f,0.f};
#pragma unroll
    for (int mt=0;mt<4;mt++)
#pragma unroll
        for (int rt=0;rt<2;rt++){ accq[mt][rt]=fz; acck[mt][rt]=fz; accv[mt][rt]=fz; }
    for (int n=0;n<8;n++){
        f4v cacc[4][2];
#pragma unroll
        for (int mt=0;mt<4;mt++)
#pragma unroll
            for (int rt=0;rt<2;rt++) cacc[mt][rt]=fz;
        const size_t bbase = (size_t)(n*512 + r0)*1024;
        for (int s=0;s<32;s++){
            const int d0 = s*32;
            __syncthreads();
            gld_lds16(xb + (size_t)(m0 + w*16 + srow)*Dd + d0 + schunk,      As + w*512);
            gld_lds16(xb + (size_t)(m0 + 64 + w*16 + srow)*Dd + d0 + schunk, As + 2048 + w*512);
            gld_lds16(cnT + bbase + (size_t)(w*16 + srow)*1024 + d0 + schunk, Bs + w*512);
            __syncthreads();
            s8v af[4], bf[2];
#pragma unroll
            for (int mt=0;mt<4;mt++) af[mt] = *(const s8v*)((const char*)As + aoff[mt]);
#pragma unroll
            for (int rt=0;rt<2;rt++) bf[rt] = *(const s8v*)((const char*)Bs + boff[rt]);
#pragma unroll
            for (int mt=0;mt<4;mt++)
#pragma unroll
                for (int rt=0;rt<2;rt++)
                    cacc[mt][rt] = __builtin_amdgcn_mfma_f32_16x16x32_bf16(af[mt], bf[rt], cacc[mt][rt], 0,0,0);
        }
#pragma unroll
        for (int mt=0;mt<4;mt++){
            const int mq4 = wm + mt*16 + ((lane>>4)<<2);
            f4v w0 = *(const f4v*)&wL[0][n][mq4];
            f4v w1 = *(const f4v*)&wL[1][n][mq4];
            f4v w2 = *(const f4v*)&wL[2][n][mq4];
#pragma unroll
            for (int rt=0;rt<2;rt++){
                accq[mt][rt] += w0 * cacc[mt][rt];
                acck[mt][rt] += w1 * cacc[mt][rt];
                accv[mt][rt] += w2 * cacc[mt][rt];
            }
        }
    }
#pragma unroll
    for (int mt=0;mt<4;mt++)
#pragma unroll
        for (int rt=0;rt<2;rt++){
            const int rcol = r0 + wr + rt*16 + (lane&15);
#pragma unroll
            for (int e=0;e<4;e++){
                const int m = m0 + wm + mt*16 + ((lane>>4)<<2) + e;
                const size_t idx = (size_t)m*Rr + rcol;
                qb[idx] = f2bf(accq[mt][rt][e]);
                kb[idx] = f2bf(acck[mt][rt][e]);
                vb[idx] = f2bf(accv[mt][rt][e]);
            }
        }
}

// ---------------- causal flash attention (fp32 compute, bf16 i/o) ----------------
__global__ __launch_bounds__(256) void k_attn(
    const u16* __restrict__ qb, const u16* __restrict__ kb, const u16* __restrict__ vb,
    u16* __restrict__ ab)
{
    __shared__ float Qt[64][68];
    __shared__ float KSt[64][68];
    __shared__ float Vs[64][68];
    __shared__ float m_l[64], l_l[64], al_l[64];
    const int tid = threadIdx.x;
    const int qt = blockIdx.x, bh = blockIdx.y;
    const int b = bh>>3, h = bh&7;
    const int ty = tid>>4, tx = tid&15;
    const int lrow = tid>>2, lq = tid&3;
    const u16* qbase = qb + (size_t)(b*Ss)*Rr + h*DHd;
    const u16* kbase = kb + (size_t)(b*Ss)*Rr + h*DHd;
    const u16* vbase = vb + (size_t)(b*Ss)*Rr + h*DHd;
#pragma unroll
    for (int jj=lq; jj<16; jj+=4){
        ushort4 v = *(const ushort4*)(qbase + (size_t)(qt*64+lrow)*Rr + jj*4);
        Qt[jj*4+0][lrow]=bf2f(v.x); Qt[jj*4+1][lrow]=bf2f(v.y);
        Qt[jj*4+2][lrow]=bf2f(v.z); Qt[jj*4+3][lrow]=bf2f(v.w);
    }
    if (tid < 64){ m_l[tid] = -1e30f; l_l[tid] = 0.f; }
    float o[4][4]={};
    for (int kt=0; kt<=qt; kt++){
        __syncthreads();
#pragma unroll
        for (int jj=lq; jj<16; jj+=4){
            ushort4 kv = *(const ushort4*)(kbase + (size_t)(kt*64+lrow)*Rr + jj*4);
            KSt[jj*4+0][lrow]=bf2f(kv.x); KSt[jj*4+1][lrow]=bf2f(kv.y);
            KSt[jj*4+2][lrow]=bf2f(kv.z); KSt[jj*4+3][lrow]=bf2f(kv.w);
            ushort4 vv = *(const ushort4*)(vbase + (size_t)(kt*64+lrow)*Rr + jj*4);
            Vs[lrow][jj*4+0]=bf2f(vv.x); Vs[lrow][jj*4+1]=bf2f(vv.y);
            Vs[lrow][jj*4+2]=bf2f(vv.z); Vs[lrow][jj*4+3]=bf2f(vv.w);
        }
        __syncthreads();
        float s[4][4]={};
#pragma unroll
        for (int d=0; d<64; d++){
            float4 q4 = *(float4*)&Qt[d][ty*4];
            float4 k4 = *(float4*)&KSt[d][tx*4];
            float qv[4]={q4.x,q4.y,q4.z,q4.w};
            float kv[4]={k4.x,k4.y,k4.z,k4.w};
#pragma unroll
            for (int i=0;i<4;i++)
#pragma unroll
                for (int j=0;j<4;j++) s[i][j] += qv[i]*kv[j];
        }
        __syncthreads();
#pragma unroll
        for (int i=0;i<4;i++){
            const int qg = qt*64 + ty*4 + i;
#pragma unroll
            for (int j=0;j<4;j++){
                const int kg = kt*64 + tx*4 + j;
                float sv = s[i][j]*0.125f;
                if (kg > qg) sv = -1e30f;
                KSt[tx*4+j][ty*4+i] = sv;
            }
        }
        __syncthreads();
        if (tid < 64){
            const int r = tid;
            const float mo = m_l[r];
            float mt = mo;
#pragma unroll 8
            for (int j=0;j<64;j++) mt = fmaxf(mt, KSt[j][r]);
            const float al = expf(mo - mt);
            float sum = 0.f;
#pragma unroll 8
            for (int j=0;j<64;j++){
                float p = expf(KSt[j][r] - mt);
                KSt[j][r] = p; sum += p;
            }
            l_l[r] = l_l[r]*al + sum;
            m_l[r] = mt;
            al_l[r] = al;
        }
        __syncthreads();
        float alr[4];
#pragma unroll
        for (int i=0;i<4;i++) alr[i] = al_l[ty*4+i];
#pragma unroll
        for (int i=0;i<4;i++)
#pragma unroll
            for (int j=0;j<4;j++) o[i][j] *= alr[i];
#pragma unroll
        for (int jk=0;jk<64;jk++){
            float4 p4 = *(float4*)&KSt[jk][ty*4];
            float4 v4 = *(float4*)&Vs[jk][tx*4];
            float pv[4]={p4.x,p4.y,p4.z,p4.w};
            float vv[4]={v4.x,v4.y,v4.z,v4.w};
#pragma unroll
            for (int i=0;i<4;i++)
#pragma unroll
                for (int j=0;j<4;j++) o[i][j] += pv[i]*vv[j];
        }
    }
    u16* abase = ab + (size_t)(b*Ss)*Rr + h*DHd;
#pragma unroll
    for (int i=0;i<4;i++){
        const int qg = qt*64 + ty*4 + i;
        const float inv = 1.f / l_l[ty*4+i];
        ushort4 st;
        st.x = f2bf(o[i][0]*inv); st.y = f2bf(o[i][1]*inv);
        st.z = f2bf(o[i][2]*inv); st.w = f2bf(o[i][3]*inv);
        *(ushort4*)(abase + (size_t)qg*Rr + tx*4) = st;
    }
}

// ---------------- output router softmax weights [M,8] (ab bf16, wro fp32) ----------------
__global__ __launch_bounds__(64) void k_router_o(
    const u16* __restrict__ ab, const float* __restrict__ wro, float* __restrict__ wo)
{
    const int m = blockIdx.x, lane = threadIdx.x;
    float a[8];
#pragma unroll
    for (int r=0;r<8;r++) a[r]=0.f;
#pragma unroll
    for (int i=0;i<2;i++){
        const size_t d0 = i*256 + lane*4;
        ushort4 av4 = *(const ushort4*)(ab + (size_t)m*Rr + d0);
        float a0=bf2f(av4.x), a1=bf2f(av4.y), a2=bf2f(av4.z), a3=bf2f(av4.w);
#pragma unroll
        for (int r=0;r<8;r++){
            float4 w4 = *(const float4*)(wro + (size_t)r*Rr + d0);
            a[r] += a0*w4.x + a1*w4.y + a2*w4.z + a3*w4.w;
        }
    }
#pragma unroll
    for (int r=0;r<8;r++)
#pragma unroll
        for (int off=32;off>=1;off>>=1) a[r]+=__shfl_xor(a[r],off);
    float mx=a[0];
#pragma unroll
    for (int r=1;r<8;r++) mx=fmaxf(mx,a[r]);
    float e[8], s=0.f;
#pragma unroll
    for (int r=0;r<8;r++){ e[r]=expf(a[r]-mx); s+=e[r]; }
    if (lane < 8) wo[m*8+lane] = e[lane]/s;
}

// ---------------- expand: out [M,D] fp32 via MFMA ----------------
__global__ __launch_bounds__(256) void k_expand_mfma(
    const u16* __restrict__ ab, const u16* __restrict__ enT,
    const float* __restrict__ wo, float* __restrict__ out)
{
    __shared__ __align__(16) u16 As[128*32];
    __shared__ __align__(16) u16 Bs[64*32];
    __shared__ float wL[8][128];
    const int tid = threadIdx.x;
    const int lane = tid & 63, w = tid >> 6;
    const int m0 = blockIdx.y*128, dB0 = blockIdx.x*64;
    for (int i = tid; i < 8*128; i += 256){
        const int n = i >> 7, ml = i & 127;
        wL[n][ml] = wo[(size_t)(m0+ml)*8 + n];
    }
    const int wm = (w&1)*64, wr = (w>>1)*32;
    const int swz = ((lane>>4) ^ (lane&3));
    int aoff[4], boff[2];
#pragma unroll
    for (int mt=0;mt<4;mt++) aoff[mt] = (wm + mt*16 + (lane&15))*64 + swz*16;
#pragma unroll
    for (int rt=0;rt<2;rt++) boff[rt] = (wr + rt*16 + (lane&15))*64 + swz*16;
    const int srow = lane>>2, sq = lane&3;
    const int schunk = (sq ^ (srow&3))<<3;
    f4v acc[4][2];
    const f4v fz = {0.f,0.f,0.f,0.f};
#pragma unroll
    for (int mt=0;mt<4;mt++)
#pragma unroll
        for (int rt=0;rt<2;rt++) acc[mt][rt]=fz;
    for (int n=0;n<8;n++){
        f4v cacc[4][2];
#pragma unroll
        for (int mt=0;mt<4;mt++)
#pragma unroll
            for (int rt=0;rt<2;rt++) cacc[mt][rt]=fz;
        const size_t bbase = (size_t)(n*1024 + dB0)*512;
        for (int s=0;s<16;s++){
            const int r0k = s*32;
            __syncthreads();
            gld_lds16(ab + (size_t)(m0 + w*16 + srow)*Rr + r0k + schunk,      As + w*512);
            gld_lds16(ab + (size_t)(m0 + 64 + w*16 + srow)*Rr + r0k + schunk, As + 2048 + w*512);
            gld_lds16(enT + bbase + (size_t)(w*16 + srow)*512 + r0k + schunk, Bs + w*512);
            __syncthreads();
            s8v af[4], bf[2];
#pragma unroll
            for (int mt=0;mt<4;mt++) af[mt] = *(const s8v*)((const char*)As + aoff[mt]);
#pragma unroll
            for (int rt=0;rt<2;rt++) bf[rt] = *(const s8v*)((const char*)Bs + boff[rt]);
#pragma unroll
            for (int mt=0;mt<4;mt++)
#pragma unroll
                for (int rt=0;rt<2;rt++)
                    cacc[mt][rt] = __builtin_amdgcn_mfma_f32_16x16x32_bf16(af[mt], bf[rt], cacc[mt][rt], 0,0,0);
        }
#pragma unroll
        for (int mt=0;mt<4;mt++){
            const int mq4 = wm + mt*16 + ((lane>>4)<<2);
            f4v w0 = *(const f4v*)&wL[n][mq4];
#pragma unroll
            for (int rt=0;rt<2;rt++) acc[mt][rt] += w0 * cacc[mt][rt];
        }
    }
#pragma unroll
    for (int mt=0;mt<4;mt++)
#pragma unroll
        for (int rt=0;rt<2;rt++){
            const int dcol = dB0 + wr + rt*16 + (lane&15);
#pragma unroll
            for (int e=0;e<4;e++){
                const int m = m0 + wm + mt*16 + ((lane>>4)<<2) + e;
                out[(size_t)m*Dd + dcol] = acc[mt][rt][e];   // fp32 output
            }
        }
}

extern "C" void kernel_launch(void* const* d_in, const int* in_sizes, int n_in,
                              void* d_out, int out_size, void* d_ws, size_t ws_size,
                              hipStream_t stream) {
    (void)in_sizes; (void)n_in; (void)out_size; (void)ws_size;
    const float* x   = (const float*)d_in[0];
    // d_in[1] = causal mask — deterministic, unused
    const float* cn  = (const float*)d_in[2];
    const float* en  = (const float*)d_in[3];
    const float* wrq = (const float*)d_in[4];
    const float* wrk = (const float*)d_in[5];
    const float* wrv = (const float*)d_in[6];
    const float* wro = (const float*)d_in[7];

    float* ws = (float*)d_ws;
    float* wq = ws;                          // [M,8] f32
    float* wk = wq + Mm*8;
    float* wv = wk + Mm*8;
    float* wo = wv + Mm*8;
    u16* xb  = (u16*)(wo + Mm*8);            // [M,D] bf16
    u16* qb  = xb + (size_t)Mm*Dd;           // [M,R] bf16
    u16* kb  = qb + (size_t)Mm*Rr;
    u16* vb  = kb + (size_t)Mm*Rr;
    u16* ab  = vb + (size_t)Mm*Rr;           // attention out [M,R] bf16
    u16* cnT = ab + (size_t)Mm*Rr;           // [8][R][D] bf16
    u16* enT = cnT + (size_t)8*Rr*Dd;        // [8][D][R] bf16

    k_f2b<<<Mm*Dd/1024, 256, 0, stream>>>(x, xb);
    k_transpose_f2b<<<dim3(Dd/64, Rr/64, 8), 256, 0, stream>>>(cn, cnT, Dd, Rr);
    k_transpose_f2b<<<dim3(Rr/64, Dd/64, 8), 256, 0, stream>>>(en, enT, Rr, Dd);
    k_router_qkv<<<Mm, 64, 0, stream>>>(x, wrq, wrk, wrv, wq, wk, wv);
    k_compress_mfma<<<dim3(Rr/64, Mm/128), 256, 0, stream>>>(xb, cnT, wq, wk, wv, qb, kb, vb);
    k_attn<<<dim3(Ss/64, Bb*Hh), 256, 0, stream>>>(qb, kb, vb, ab);
    k_router_o<<<Mm, 64, 0, stream>>>(ab, wro, wo);
    k_expand_mfma<<<dim3(Dd/64, Mm/128), 256, 0, stream>>>(ab, enT, wo, (float*)d_out);
}

// Round 5
// 547.886 us; speedup vs baseline: 5.8568x; 2.2737x over previous
//
#include <hip/hip_runtime.h>
#include <hip/hip_bf16.h>

typedef unsigned short u16;
typedef __attribute__((ext_vector_type(8))) short s8v;   // 8 bf16 (4 VGPRs) MFMA A/B frag
typedef __attribute__((ext_vector_type(4))) float f4v;   // MFMA C/D frag

#define Bb 4
#define Ss 2048
#define Dd 1024
#define Rr 512
#define Hh 8
#define DHd 64
#define Mm 8192   // B*S

__device__ __forceinline__ float bf2f(u16 u){
    union { unsigned int i; float f; } v; v.i = ((unsigned int)u)<<16; return v.f;
}
__device__ __forceinline__ u16 f2bf(float f){
    __hip_bfloat16 h = __float2bfloat16(f);
    return *(u16*)&h;
}
__device__ __forceinline__ void gld_lds16(const u16* g, u16* l){
    // async global->LDS, 16B/lane; LDS dest = (wave-uniform base) + lane*16
    __builtin_amdgcn_global_load_lds((const __attribute__((address_space(1))) unsigned int*)g,
                                     (__attribute__((address_space(3))) unsigned int*)l, 16, 0, 0);
}

// ---------------- fp32 -> bf16 bulk convert ----------------
__global__ __launch_bounds__(256) void k_f2b(
    const float* __restrict__ in, u16* __restrict__ out)
{
    const size_t i = (size_t)blockIdx.x*256 + threadIdx.x;
    float4 v = ((const float4*)in)[i];
    ushort4 o;
    o.x = f2bf(v.x); o.y = f2bf(v.y); o.z = f2bf(v.z); o.w = f2bf(v.w);
    ((ushort4*)out)[i] = o;
}

// ---------------- transpose + convert: src[n][A][B] f32 -> dst[n][B][A] bf16 ----------------
__global__ __launch_bounds__(256) void k_transpose_f2b(
    const float* __restrict__ src, u16* __restrict__ dst, int A, int B)
{
    __shared__ float t[64][65];
    const int a0 = blockIdx.x*64, b0 = blockIdx.y*64, n = blockIdx.z;
    const size_t sbase = (size_t)n*A*B;
    const int r = threadIdx.x>>4, c = threadIdx.x&15;
#pragma unroll
    for (int p=0;p<4;p++){
        const int ar = r + p*16;
        float4 v = *(const float4*)(src + sbase + (size_t)(a0+ar)*B + b0 + c*4);
        t[ar][c*4+0]=v.x; t[ar][c*4+1]=v.y; t[ar][c*4+2]=v.z; t[ar][c*4+3]=v.w;
    }
    __syncthreads();
#pragma unroll
    for (int p=0;p<4;p++){
        const int br = r + p*16;
        ushort4 o;
        o.x = f2bf(t[c*4+0][br]); o.y = f2bf(t[c*4+1][br]);
        o.z = f2bf(t[c*4+2][br]); o.w = f2bf(t[c*4+3][br]);
        *(ushort4*)(dst + sbase + (size_t)(b0+br)*A + a0 + c*4) = o;
    }
}

// ---------------- V transpose: vb [M][R] bf16 -> vtb [BH][DH][S] bf16 ----------------
__global__ __launch_bounds__(256) void k_transpose_v(
    const u16* __restrict__ vb, u16* __restrict__ vtb)
{
    __shared__ u16 T[64][72];   // row stride 144B (16B-aligned)
    const int st = blockIdx.x, bh = blockIdx.y;
    const int b = bh>>3, h = bh&7;
    const int tid = threadIdx.x;
    const int srow = tid>>2, c4 = tid&3;
    // load 64 s-rows x 64 d (bf16), coalesced
#pragma unroll
    for (int p=0;p<2;p++){
        const int ch = c4 + p*4;
        s8v v = *(const s8v*)(vb + (size_t)(b*Ss + st*64 + srow)*Rr + h*DHd + ch*8);
        *(s8v*)&T[srow][ch*8] = v;
    }
    __syncthreads();
    const int dl = tid & 63, w2 = tid>>6;
#pragma unroll
    for (int p=0;p<2;p++){
        const int sc = w2*2 + p;     // s-chunk 0..7
        u16 o[8];
#pragma unroll
        for (int j=0;j<8;j++) o[j] = T[sc*8+j][dl];
        *(s8v*)(vtb + (size_t)bh*DHd*Ss + (size_t)dl*Ss + st*64 + sc*8) = *(s8v*)o;
    }
}

// ---------------- q/k/v router softmax weights [M,8] each (fp32 in) ----------------
__global__ __launch_bounds__(64) void k_router_qkv(
    const float* __restrict__ x, const float* __restrict__ wrq,
    const float* __restrict__ wrk, const float* __restrict__ wrv,
    float* __restrict__ wq, float* __restrict__ wk, float* __restrict__ wv)
{
    const int m = blockIdx.x, lane = threadIdx.x;
    float aq[8], ak[8], av[8];
#pragma unroll
    for (int r=0;r<8;r++){ aq[r]=0.f; ak[r]=0.f; av[r]=0.f; }
#pragma unroll
    for (int i=0;i<4;i++){
        const size_t d0 = i*256 + lane*4;
        float4 xv = *(const float4*)(x + (size_t)m*Dd + d0);
#pragma unroll
        for (int r=0;r<8;r++){
            float4 q4 = *(const float4*)(wrq + (size_t)r*Dd + d0);
            aq[r] += xv.x*q4.x + xv.y*q4.y + xv.z*q4.z + xv.w*q4.w;
            float4 k4 = *(const float4*)(wrk + (size_t)r*Dd + d0);
            ak[r] += xv.x*k4.x + xv.y*k4.y + xv.z*k4.z + xv.w*k4.w;
            float4 v4 = *(const float4*)(wrv + (size_t)r*Dd + d0);
            av[r] += xv.x*v4.x + xv.y*v4.y + xv.z*v4.z + xv.w*v4.w;
        }
    }
#pragma unroll
    for (int r=0;r<8;r++){
#pragma unroll
        for (int off=32;off>=1;off>>=1){
            aq[r]+=__shfl_xor(aq[r],off);
            ak[r]+=__shfl_xor(ak[r],off);
            av[r]+=__shfl_xor(av[r],off);
        }
    }
    float mq=aq[0], mk=ak[0], mv=av[0];
#pragma unroll
    for (int r=1;r<8;r++){ mq=fmaxf(mq,aq[r]); mk=fmaxf(mk,ak[r]); mv=fmaxf(mv,av[r]); }
    float eq[8], ek[8], ev[8], sq=0.f, sk=0.f, sv=0.f;
#pragma unroll
    for (int r=0;r<8;r++){
        eq[r]=expf(aq[r]-mq); sq+=eq[r];
        ek[r]=expf(ak[r]-mk); sk+=ek[r];
        ev[r]=expf(av[r]-mv); sv+=ev[r];
    }
    if (lane < 8)        wq[m*8+lane]    = eq[lane]/sq;
    else if (lane < 16)  wk[m*8+lane-8]  = ek[lane-8]/sk;
    else if (lane < 24)  wv[m*8+lane-16] = ev[lane-16]/sv;
}

// ---------------- compress: q,k,v [M,R] bf16 via MFMA ----------------
__global__ __launch_bounds__(256) void k_compress_mfma(
    const u16* __restrict__ xb, const u16* __restrict__ cnT,
    const float* __restrict__ wq, const float* __restrict__ wk, const float* __restrict__ wv,
    u16* __restrict__ qb, u16* __restrict__ kb, u16* __restrict__ vb)
{
    __shared__ __align__(16) u16 As[128*32];   // [m][k32], 16B chunks XOR-swizzled
    __shared__ __align__(16) u16 Bs[64*32];    // [r][k32]
    __shared__ float wL[3][8][128];
    const int tid = threadIdx.x;
    const int lane = tid & 63, w = tid >> 6;
    const int m0 = blockIdx.y*128, r0 = blockIdx.x*64;
    for (int i = tid; i < 3*8*128; i += 256){
        const int t = i >> 10, rem = i & 1023, n = rem >> 7, ml = rem & 127;
        const float* wsrc = (t==0)? wq : (t==1)? wk : wv;
        wL[t][n][ml] = wsrc[(size_t)(m0+ml)*8 + n];
    }
    const int wm = (w&1)*64, wr = (w>>1)*32;
    const int swz = ((lane>>4) ^ (lane&3));
    int aoff[4], boff[2];
#pragma unroll
    for (int mt=0;mt<4;mt++) aoff[mt] = (wm + mt*16 + (lane&15))*64 + swz*16;  // bytes
#pragma unroll
    for (int rt=0;rt<2;rt++) boff[rt] = (wr + rt*16 + (lane&15))*64 + swz*16;
    const int srow = lane>>2, sq = lane&3;
    const int schunk = (sq ^ (srow&3))<<3;
    f4v accq[4][2], acck[4][2], accv[4][2];
    const f4v fz = {0.f,0.f,0.f,0.f};
#pragma unroll
    for (int mt=0;mt<4;mt++)
#pragma unroll
        for (int rt=0;rt<2;rt++){ accq[mt][rt]=fz; acck[mt][rt]=fz; accv[mt][rt]=fz; }
    for (int n=0;n<8;n++){
        f4v cacc[4][2];
#pragma unroll
        for (int mt=0;mt<4;mt++)
#pragma unroll
            for (int rt=0;rt<2;rt++) cacc[mt][rt]=fz;
        const size_t bbase = (size_t)(n*512 + r0)*1024;
        for (int s=0;s<32;s++){
            const int d0 = s*32;
            __syncthreads();
            gld_lds16(xb + (size_t)(m0 + w*16 + srow)*Dd + d0 + schunk,      As + w*512);
            gld_lds16(xb + (size_t)(m0 + 64 + w*16 + srow)*Dd + d0 + schunk, As + 2048 + w*512);
            gld_lds16(cnT + bbase + (size_t)(w*16 + srow)*1024 + d0 + schunk, Bs + w*512);
            __syncthreads();
            s8v af[4], bf[2];
#pragma unroll
            for (int mt=0;mt<4;mt++) af[mt] = *(const s8v*)((const char*)As + aoff[mt]);
#pragma unroll
            for (int rt=0;rt<2;rt++) bf[rt] = *(const s8v*)((const char*)Bs + boff[rt]);
#pragma unroll
            for (int mt=0;mt<4;mt++)
#pragma unroll
                for (int rt=0;rt<2;rt++)
                    cacc[mt][rt] = __builtin_amdgcn_mfma_f32_16x16x32_bf16(af[mt], bf[rt], cacc[mt][rt], 0,0,0);
        }
#pragma unroll
        for (int mt=0;mt<4;mt++){
            const int mq4 = wm + mt*16 + ((lane>>4)<<2);
            f4v w0 = *(const f4v*)&wL[0][n][mq4];
            f4v w1 = *(const f4v*)&wL[1][n][mq4];
            f4v w2 = *(const f4v*)&wL[2][n][mq4];
#pragma unroll
            for (int rt=0;rt<2;rt++){
                accq[mt][rt] += w0 * cacc[mt][rt];
                acck[mt][rt] += w1 * cacc[mt][rt];
                accv[mt][rt] += w2 * cacc[mt][rt];
            }
        }
    }
#pragma unroll
    for (int mt=0;mt<4;mt++)
#pragma unroll
        for (int rt=0;rt<2;rt++){
            const int rcol = r0 + wr + rt*16 + (lane&15);
#pragma unroll
            for (int e=0;e<4;e++){
                const int m = m0 + wm + mt*16 + ((lane>>4)<<2) + e;
                const size_t idx = (size_t)m*Rr + rcol;
                qb[idx] = f2bf(accq[mt][rt][e]);
                kb[idx] = f2bf(acck[mt][rt][e]);
                vb[idx] = f2bf(accv[mt][rt][e]);
            }
        }
}

// ---------------- MFMA causal flash attention ----------------
// 64x64 tiles, 4 waves/block, wave owns 16 Q rows. Q in regs; K,Vt staged
// via global_load_lds w/ XOR-chunk swizzle; P C->A layout via per-wave LDS.
__global__ __launch_bounds__(256) void k_attn_mfma(
    const u16* __restrict__ qb, const u16* __restrict__ kb, const u16* __restrict__ vtb,
    u16* __restrict__ ab)
{
    __shared__ __align__(16) u16 Ks[64*64];     // [key][d], chunk-swizzled
    __shared__ __align__(16) u16 Vt[64*64];     // [d][key], chunk-swizzled
    __shared__ __align__(16) u16 Ps[4*16*64];   // per-wave P [qrow16][key64], swizzled
    const int tid = threadIdx.x;
    const int lane = tid & 63, w = tid >> 6;
    const int quad = lane >> 4, l15 = lane & 15;
    const int bh = blockIdx.x;
    const int yq = blockIdx.y;
    const int qt = (yq < 16) ? yq : (47 - yq);   // balance: CU's 4 blocks sum const
    const int b = bh >> 3, h = bh & 7;
    const u16* qbase = qb + (size_t)(b*Ss)*Rr + h*DHd;
    const u16* kbase = kb + (size_t)(b*Ss)*Rr + h*DHd;
    const u16* vtbase = vtb + (size_t)bh*DHd*Ss;
    // Q fragments (A-layout): row = lane&15, k = quad*8+j
    s8v qf[2];
    {
        const size_t qrow = qt*64 + w*16 + l15;
        qf[0] = *(const s8v*)(qbase + qrow*Rr + quad*8);
        qf[1] = *(const s8v*)(qbase + qrow*Rr + 32 + quad*8);
    }
    const f4v fz = {0.f,0.f,0.f,0.f};
    f4v oacc[4]; 
#pragma unroll
    for (int dn=0;dn<4;dn++) oacc[dn]=fz;
    float m_e[4], l_e[4];
#pragma unroll
    for (int e=0;e<4;e++){ m_e[e] = -1e30f; l_e[e] = 0.f; }
    // staging lane constants: 8 rows x 8 chunks per wave-issue
    const int srow = lane>>3;                  // row within 8-row slab
    const int sch  = (lane&7) ^ srow;          // swizzled source chunk (= pos ^ (row&7))
    u16* pw = Ps + w*1024;
    for (int kt=0; kt<=qt; kt++){
        __syncthreads();
        // stage K tile [64 keys][64 d] and Vt tile [64 d][64 keys]
        gld_lds16(kbase + (size_t)(kt*64 + w*8 + srow)*Rr + sch*8,        Ks + w*512);
        gld_lds16(kbase + (size_t)(kt*64 + 32 + w*8 + srow)*Rr + sch*8,   Ks + 2048 + w*512);
        gld_lds16(vtbase + (size_t)(w*8 + srow)*Ss + kt*64 + sch*8,       Vt + w*512);
        gld_lds16(vtbase + (size_t)(32 + w*8 + srow)*Ss + kt*64 + sch*8,  Vt + 2048 + w*512);
        __syncthreads();
        // S = Q K^T : rows = quad*4+e, cols = cn*16+l15
        f4v s[4];
#pragma unroll
        for (int cn=0;cn<4;cn++) s[cn]=fz;
#pragma unroll
        for (int cn=0;cn<4;cn++)
#pragma unroll
            for (int kc=0;kc<2;kc++){
                s8v bf = *(const s8v*)(Ks + (cn*16 + l15)*64 + (((kc*4 + quad) ^ (l15&7))<<3));
                s[cn] = __builtin_amdgcn_mfma_f32_16x16x32_bf16(qf[kc], bf, s[cn], 0,0,0);
            }
        // scale + causal mask (only diagonal tile needs mask)
        if (kt == qt){
            const int qg = qt*64 + w*16 + quad*4;
            const int kg = kt*64 + l15;
#pragma unroll
            for (int cn=0;cn<4;cn++)
#pragma unroll
                for (int e=0;e<4;e++){
                    float sv = s[cn][e]*0.125f;
                    s[cn][e] = ((kg + cn*16) > (qg + e)) ? -1e30f : sv;
                }
        } else {
#pragma unroll
            for (int cn=0;cn<4;cn++)
#pragma unroll
                for (int e=0;e<4;e++) s[cn][e] *= 0.125f;
        }
        // online softmax per row (row group = 16 lanes sharing quad)
        float al_e[4];
#pragma unroll
        for (int e=0;e<4;e++){
            float mx = fmaxf(fmaxf(s[0][e],s[1][e]), fmaxf(s[2][e],s[3][e]));
#pragma unroll
            for (int off=1;off<16;off<<=1) mx = fmaxf(mx, __shfl_xor(mx, off));
            const float mt = fmaxf(m_e[e], mx);
            const float al = __expf(m_e[e] - mt);
            m_e[e] = mt;
            float sum = 0.f;
#pragma unroll
            for (int cn=0;cn<4;cn++){
                float p = __expf(s[cn][e] - mt);
                s[cn][e] = p; sum += p;
            }
#pragma unroll
            for (int off=1;off<16;off<<=1) sum += __shfl_xor(sum, off);
            l_e[e] = l_e[e]*al + sum;
            al_e[e] = al;
        }
        // write P (C-layout) to per-wave LDS in swizzled A-readable layout
#pragma unroll
        for (int e=0;e<4;e++){
            const int row = quad*4 + e;
#pragma unroll
            for (int cn=0;cn<4;cn++){
                const int key = cn*16 + l15;
                pw[row*64 + (((key>>3) ^ (row&7))<<3) + (key&7)] = f2bf(s[cn][e]);
            }
        }
        // rescale O, then O += P V
#pragma unroll
        for (int dn=0;dn<4;dn++)
#pragma unroll
            for (int e=0;e<4;e++) oacc[dn][e] *= al_e[e];
#pragma unroll
        for (int dn=0;dn<4;dn++)
#pragma unroll
            for (int kc=0;kc<2;kc++){
                s8v pf = *(const s8v*)(pw + l15*64 + (((kc*4 + quad) ^ (l15&7))<<3));
                s8v vf = *(const s8v*)(Vt + (dn*16 + l15)*64 + (((kc*4 + quad) ^ (l15&7))<<3));
                oacc[dn] = __builtin_amdgcn_mfma_f32_16x16x32_bf16(pf, vf, oacc[dn], 0,0,0);
            }
    }
    u16* abase = ab + (size_t)(b*Ss + qt*64 + w*16)*Rr + h*DHd;
#pragma unroll
    for (int e=0;e<4;e++){
        const float inv = 1.f / l_e[e];
#pragma unroll
        for (int dn=0;dn<4;dn++)
            abase[(size_t)(quad*4+e)*Rr + dn*16 + l15] = f2bf(oacc[dn][e]*inv);
    }
}

// ---------------- output router softmax weights [M,8] (ab bf16, wro fp32) ----------------
__global__ __launch_bounds__(64) void k_router_o(
    const u16* __restrict__ ab, const float* __restrict__ wro, float* __restrict__ wo)
{
    const int m = blockIdx.x, lane = threadIdx.x;
    float a[8];
#pragma unroll
    for (int r=0;r<8;r++) a[r]=0.f;
#pragma unroll
    for (int i=0;i<2;i++){
        const size_t d0 = i*256 + lane*4;
        ushort4 av4 = *(const ushort4*)(ab + (size_t)m*Rr + d0);
        float a0=bf2f(av4.x), a1=bf2f(av4.y), a2=bf2f(av4.z), a3=bf2f(av4.w);
#pragma unroll
        for (int r=0;r<8;r++){
            float4 w4 = *(const float4*)(wro + (size_t)r*Rr + d0);
            a[r] += a0*w4.x + a1*w4.y + a2*w4.z + a3*w4.w;
        }
    }
#pragma unroll
    for (int r=0;r<8;r++)
#pragma unroll
        for (int off=32;off>=1;off>>=1) a[r]+=__shfl_xor(a[r],off);
    float mx=a[0];
#pragma unroll
    for (int r=1;r<8;r++) mx=fmaxf(mx,a[r]);
    float e[8], s=0.f;
#pragma unroll
    for (int r=0;r<8;r++){ e[r]=expf(a[r]-mx); s+=e[r]; }
    if (lane < 8) wo[m*8+lane] = e[lane]/s;
}

// ---------------- expand: out [M,D] fp32 via MFMA ----------------
__global__ __launch_bounds__(256) void k_expand_mfma(
    const u16* __restrict__ ab, const u16* __restrict__ enT,
    const float* __restrict__ wo, float* __restrict__ out)
{
    __shared__ __align__(16) u16 As[128*32];
    __shared__ __align__(16) u16 Bs[64*32];
    __shared__ float wL[8][128];
    const int tid = threadIdx.x;
    const int lane = tid & 63, w = tid >> 6;
    const int m0 = blockIdx.y*128, dB0 = blockIdx.x*64;
    for (int i = tid; i < 8*128; i += 256){
        const int n = i >> 7, ml = i & 127;
        wL[n][ml] = wo[(size_t)(m0+ml)*8 + n];
    }
    const int wm = (w&1)*64, wr = (w>>1)*32;
    const int swz = ((lane>>4) ^ (lane&3));
    int aoff[4], boff[2];
#pragma unroll
    for (int mt=0;mt<4;mt++) aoff[mt] = (wm + mt*16 + (lane&15))*64 + swz*16;
#pragma unroll
    for (int rt=0;rt<2;rt++) boff[rt] = (wr + rt*16 + (lane&15))*64 + swz*16;
    const int srow = lane>>2, sq = lane&3;
    const int schunk = (sq ^ (srow&3))<<3;
    f4v acc[4][2];
    const f4v fz = {0.f,0.f,0.f,0.f};
#pragma unroll
    for (int mt=0;mt<4;mt++)
#pragma unroll
        for (int rt=0;rt<2;rt++) acc[mt][rt]=fz;
    for (int n=0;n<8;n++){
        f4v cacc[4][2];
#pragma unroll
        for (int mt=0;mt<4;mt++)
#pragma unroll
            for (int rt=0;rt<2;rt++) cacc[mt][rt]=fz;
        const size_t bbase = (size_t)(n*1024 + dB0)*512;
        for (int s=0;s<16;s++){
            const int r0k = s*32;
            __syncthreads();
            gld_lds16(ab + (size_t)(m0 + w*16 + srow)*Rr + r0k + schunk,      As + w*512);
            gld_lds16(ab + (size_t)(m0 + 64 + w*16 + srow)*Rr + r0k + schunk, As + 2048 + w*512);
            gld_lds16(enT + bbase + (size_t)(w*16 + srow)*512 + r0k + schunk, Bs + w*512);
            __syncthreads();
            s8v af[4], bf[2];
#pragma unroll
            for (int mt=0;mt<4;mt++) af[mt] = *(const s8v*)((const char*)As + aoff[mt]);
#pragma unroll
            for (int rt=0;rt<2;rt++) bf[rt] = *(const s8v*)((const char*)Bs + boff[rt]);
#pragma unroll
            for (int mt=0;mt<4;mt++)
#pragma unroll
                for (int rt=0;rt<2;rt++)
                    cacc[mt][rt] = __builtin_amdgcn_mfma_f32_16x16x32_bf16(af[mt], bf[rt], cacc[mt][rt], 0,0,0);
        }
#pragma unroll
        for (int mt=0;mt<4;mt++){
            const int mq4 = wm + mt*16 + ((lane>>4)<<2);
            f4v w0 = *(const f4v*)&wL[n][mq4];
#pragma unroll
            for (int rt=0;rt<2;rt++) acc[mt][rt] += w0 * cacc[mt][rt];
        }
    }
#pragma unroll
    for (int mt=0;mt<4;mt++)
#pragma unroll
        for (int rt=0;rt<2;rt++){
            const int dcol = dB0 + wr + rt*16 + (lane&15);
#pragma unroll
            for (int e=0;e<4;e++){
                const int m = m0 + wm + mt*16 + ((lane>>4)<<2) + e;
                out[(size_t)m*Dd + dcol] = acc[mt][rt][e];   // fp32 output
            }
        }
}

extern "C" void kernel_launch(void* const* d_in, const int* in_sizes, int n_in,
                              void* d_out, int out_size, void* d_ws, size_t ws_size,
                              hipStream_t stream) {
    (void)in_sizes; (void)n_in; (void)out_size; (void)ws_size;
    const float* x   = (const float*)d_in[0];
    // d_in[1] = causal mask — deterministic, unused
    const float* cn  = (const float*)d_in[2];
    const float* en  = (const float*)d_in[3];
    const float* wrq = (const float*)d_in[4];
    const float* wrk = (const float*)d_in[5];
    const float* wrv = (const float*)d_in[6];
    const float* wro = (const float*)d_in[7];

    float* ws = (float*)d_ws;
    float* wq = ws;                          // [M,8] f32
    float* wk = wq + Mm*8;
    float* wv = wk + Mm*8;
    float* wo = wv + Mm*8;
    u16* xb  = (u16*)(wo + Mm*8);            // [M,D] bf16
    u16* qb  = xb + (size_t)Mm*Dd;           // [M,R] bf16
    u16* kb  = qb + (size_t)Mm*Rr;
    u16* vb  = kb + (size_t)Mm*Rr;
    u16* ab  = vb + (size_t)Mm*Rr;           // attention out [M,R] bf16
    u16* cnT = ab + (size_t)Mm*Rr;           // [8][R][D] bf16
    u16* enT = cnT + (size_t)8*Rr*Dd;        // [8][D][R] bf16
    u16* vtb = enT + (size_t)8*Dd*Rr;        // [BH][DH][S] bf16

    k_f2b<<<Mm*Dd/1024, 256, 0, stream>>>(x, xb);
    k_transpose_f2b<<<dim3(Dd/64, Rr/64, 8), 256, 0, stream>>>(cn, cnT, Dd, Rr);
    k_transpose_f2b<<<dim3(Rr/64, Dd/64, 8), 256, 0, stream>>>(en, enT, Rr, Dd);
    k_router_qkv<<<Mm, 64, 0, stream>>>(x, wrq, wrk, wrv, wq, wk, wv);
    k_compress_mfma<<<dim3(Rr/64, Mm/128), 256, 0, stream>>>(xb, cnT, wq, wk, wv, qb, kb, vb);
    k_transpose_v<<<dim3(Ss/64, Bb*Hh), 256, 0, stream>>>(vb, vtb);
    k_attn_mfma<<<dim3(Bb*Hh, Ss/64), 256, 0, stream>>>(qb, kb, vtb, ab);
    k_router_o<<<Mm, 64, 0, stream>>>(ab, wro, wo);
    k_expand_mfma<<<dim3(Dd/64, Mm/128), 256, 0, stream>>>(ab, enT, wo, (float*)d_out);
}

// Round 6
// 459.462 us; speedup vs baseline: 6.9840x; 1.1925x over previous
//
#include <hip/hip_runtime.h>
#include <hip/hip_bf16.h>

typedef unsigned short u16;
typedef __attribute__((ext_vector_type(8))) short s8v;   // 8 bf16 (4 VGPRs) MFMA A/B frag
typedef __attribute__((ext_vector_type(4))) float f4v;   // MFMA C/D frag

#define Bb 4
#define Ss 2048
#define Dd 1024
#define Rr 512
#define Hh 8
#define DHd 64
#define Mm 8192   // B*S

__device__ __forceinline__ float bf2f(u16 u){
    union { unsigned int i; float f; } v; v.i = ((unsigned int)u)<<16; return v.f;
}
__device__ __forceinline__ u16 f2bf(float f){
    __hip_bfloat16 h = __float2bfloat16(f);
    return *(u16*)&h;
}
__device__ __forceinline__ void gld_lds16(const u16* g, u16* l){
    // async global->LDS, 16B/lane; LDS dest = (wave-uniform base) + lane*16
    __builtin_amdgcn_global_load_lds((const __attribute__((address_space(1))) unsigned int*)g,
                                     (__attribute__((address_space(3))) unsigned int*)l, 16, 0, 0);
}

// ---------------- fp32 -> bf16 bulk convert ----------------
__global__ __launch_bounds__(256) void k_f2b(
    const float* __restrict__ in, u16* __restrict__ out)
{
    const size_t i = (size_t)blockIdx.x*256 + threadIdx.x;
    float4 v = ((const float4*)in)[i];
    ushort4 o;
    o.x = f2bf(v.x); o.y = f2bf(v.y); o.z = f2bf(v.z); o.w = f2bf(v.w);
    ((ushort4*)out)[i] = o;
}

// ---------------- transpose + convert: src[n][A][B] f32 -> dst[n][B][A] bf16 ----------------
__global__ __launch_bounds__(256) void k_transpose_f2b(
    const float* __restrict__ src, u16* __restrict__ dst, int A, int B)
{
    __shared__ float t[64][65];
    const int a0 = blockIdx.x*64, b0 = blockIdx.y*64, n = blockIdx.z;
    const size_t sbase = (size_t)n*A*B;
    const int r = threadIdx.x>>4, c = threadIdx.x&15;
#pragma unroll
    for (int p=0;p<4;p++){
        const int ar = r + p*16;
        float4 v = *(const float4*)(src + sbase + (size_t)(a0+ar)*B + b0 + c*4);
        t[ar][c*4+0]=v.x; t[ar][c*4+1]=v.y; t[ar][c*4+2]=v.z; t[ar][c*4+3]=v.w;
    }
    __syncthreads();
#pragma unroll
    for (int p=0;p<4;p++){
        const int br = r + p*16;
        ushort4 o;
        o.x = f2bf(t[c*4+0][br]); o.y = f2bf(t[c*4+1][br]);
        o.z = f2bf(t[c*4+2][br]); o.w = f2bf(t[c*4+3][br]);
        *(ushort4*)(dst + sbase + (size_t)(b0+br)*A + a0 + c*4) = o;
    }
}

// ---------------- V transpose: vb [M][R] bf16 -> vtb [BH][DH][S] bf16 ----------------
__global__ __launch_bounds__(256) void k_transpose_v(
    const u16* __restrict__ vb, u16* __restrict__ vtb)
{
    __shared__ u16 T[64][72];   // row stride 144B (16B-aligned)
    const int st = blockIdx.x, bh = blockIdx.y;
    const int b = bh>>3, h = bh&7;
    const int tid = threadIdx.x;
    const int srow = tid>>2, c4 = tid&3;
#pragma unroll
    for (int p=0;p<2;p++){
        const int ch = c4 + p*4;
        s8v v = *(const s8v*)(vb + (size_t)(b*Ss + st*64 + srow)*Rr + h*DHd + ch*8);
        *(s8v*)&T[srow][ch*8] = v;
    }
    __syncthreads();
    const int dl = tid & 63, w2 = tid>>6;
#pragma unroll
    for (int p=0;p<2;p++){
        const int sc = w2*2 + p;
        u16 o[8];
#pragma unroll
        for (int j=0;j<8;j++) o[j] = T[sc*8+j][dl];
        *(s8v*)(vtb + (size_t)bh*DHd*Ss + (size_t)dl*Ss + st*64 + sc*8) = *(s8v*)o;
    }
}

// ---------------- q/k/v router softmax weights [M,8] each (fp32 in) ----------------
__global__ __launch_bounds__(64) void k_router_qkv(
    const float* __restrict__ x, const float* __restrict__ wrq,
    const float* __restrict__ wrk, const float* __restrict__ wrv,
    float* __restrict__ wq, float* __restrict__ wk, float* __restrict__ wv)
{
    const int m = blockIdx.x, lane = threadIdx.x;
    float aq[8], ak[8], av[8];
#pragma unroll
    for (int r=0;r<8;r++){ aq[r]=0.f; ak[r]=0.f; av[r]=0.f; }
#pragma unroll
    for (int i=0;i<4;i++){
        const size_t d0 = i*256 + lane*4;
        float4 xv = *(const float4*)(x + (size_t)m*Dd + d0);
#pragma unroll
        for (int r=0;r<8;r++){
            float4 q4 = *(const float4*)(wrq + (size_t)r*Dd + d0);
            aq[r] += xv.x*q4.x + xv.y*q4.y + xv.z*q4.z + xv.w*q4.w;
            float4 k4 = *(const float4*)(wrk + (size_t)r*Dd + d0);
            ak[r] += xv.x*k4.x + xv.y*k4.y + xv.z*k4.z + xv.w*k4.w;
            float4 v4 = *(const float4*)(wrv + (size_t)r*Dd + d0);
            av[r] += xv.x*v4.x + xv.y*v4.y + xv.z*v4.z + xv.w*v4.w;
        }
    }
#pragma unroll
    for (int r=0;r<8;r++){
#pragma unroll
        for (int off=32;off>=1;off>>=1){
            aq[r]+=__shfl_xor(aq[r],off);
            ak[r]+=__shfl_xor(ak[r],off);
            av[r]+=__shfl_xor(av[r],off);
        }
    }
    float mq=aq[0], mk=ak[0], mv=av[0];
#pragma unroll
    for (int r=1;r<8;r++){ mq=fmaxf(mq,aq[r]); mk=fmaxf(mk,ak[r]); mv=fmaxf(mv,av[r]); }
    float eq[8], ek[8], ev[8], sq=0.f, sk=0.f, sv=0.f;
#pragma unroll
    for (int r=0;r<8;r++){
        eq[r]=expf(aq[r]-mq); sq+=eq[r];
        ek[r]=expf(ak[r]-mk); sk+=ek[r];
        ev[r]=expf(av[r]-mv); sv+=ev[r];
    }
    if (lane < 8)        wq[m*8+lane]    = eq[lane]/sq;
    else if (lane < 16)  wk[m*8+lane-8]  = ek[lane-8]/sk;
    else if (lane < 24)  wv[m*8+lane-16] = ev[lane-16]/sv;
}

// ---------------- compress: q,k,v [M,R] bf16 via MFMA ----------------
// block 128m x 64r, BK=64; grid (m-fastest) so same-m blocks share an XCD.
// LDS rows chunk-swizzled: position p of row r holds 16B-chunk p^(r&7).
__global__ __launch_bounds__(256) void k_compress_mfma(
    const u16* __restrict__ xb, const u16* __restrict__ cnT,
    const float* __restrict__ wq, const float* __restrict__ wk, const float* __restrict__ wv,
    u16* __restrict__ qb, u16* __restrict__ kb, u16* __restrict__ vb)
{
    __shared__ __align__(16) u16 As[128*64];   // 16 KB
    __shared__ __align__(16) u16 Bs[64*64];    // 8 KB
    __shared__ float wL[3][8][128];
    const int tid = threadIdx.x;
    const int lane = tid & 63, w = tid >> 6;
    const int quad = lane >> 4, l15 = lane & 15;
    const int m0 = blockIdx.x*128, r0 = blockIdx.y*64;
    for (int i = tid; i < 3*8*128; i += 256){
        const int t = i >> 10, rem = i & 1023, n = rem >> 7, ml = rem & 127;
        const float* wsrc = (t==0)? wq : (t==1)? wk : wv;
        wL[t][n][ml] = wsrc[(size_t)(m0+ml)*8 + n];
    }
    const int wm = (w&1)*64, wr = (w>>1)*32;
    // staging lane constants: per issue 8 rows x 8 chunks
    const int srow = lane>>3;                 // 0..7
    const int sch  = (lane&7) ^ srow;         // source chunk for swizzled store
    f4v accq[4][2], acck[4][2], accv[4][2];
    const f4v fz = {0.f,0.f,0.f,0.f};
#pragma unroll
    for (int mt=0;mt<4;mt++)
#pragma unroll
        for (int rt=0;rt<2;rt++){ accq[mt][rt]=fz; acck[mt][rt]=fz; accv[mt][rt]=fz; }
    for (int n=0;n<8;n++){
        f4v cacc[4][2];
#pragma unroll
        for (int mt=0;mt<4;mt++)
#pragma unroll
            for (int rt=0;rt<2;rt++) cacc[mt][rt]=fz;
        const size_t bbase = (size_t)(n*512 + r0)*1024;
        for (int s=0;s<16;s++){
            const int d0 = s*64;
            __syncthreads();
            // A: 128 rows x 64 k, 4 issues of 32 rows
#pragma unroll
            for (int i=0;i<4;i++)
                gld_lds16(xb + (size_t)(m0 + i*32 + w*8 + srow)*Dd + d0 + sch*8,
                          As + (i*32 + w*8)*64);
            // B: 64 rows x 64 k, 2 issues
#pragma unroll
            for (int i=0;i<2;i++)
                gld_lds16(cnT + bbase + (size_t)(i*32 + w*8 + srow)*1024 + d0 + sch*8,
                          Bs + (i*32 + w*8)*64);
            __syncthreads();
            s8v af[4][2], bf[2][2];
#pragma unroll
            for (int mt=0;mt<4;mt++)
#pragma unroll
                for (int kc=0;kc<2;kc++)
                    af[mt][kc] = *(const s8v*)(As + (wm + mt*16 + l15)*64 + (((kc*4+quad) ^ (l15&7))<<3));
#pragma unroll
            for (int rt=0;rt<2;rt++)
#pragma unroll
                for (int kc=0;kc<2;kc++)
                    bf[rt][kc] = *(const s8v*)(Bs + (wr + rt*16 + l15)*64 + (((kc*4+quad) ^ (l15&7))<<3));
#pragma unroll
            for (int mt=0;mt<4;mt++)
#pragma unroll
                for (int rt=0;rt<2;rt++){
                    cacc[mt][rt] = __builtin_amdgcn_mfma_f32_16x16x32_bf16(af[mt][0], bf[rt][0], cacc[mt][rt], 0,0,0);
                    cacc[mt][rt] = __builtin_amdgcn_mfma_f32_16x16x32_bf16(af[mt][1], bf[rt][1], cacc[mt][rt], 0,0,0);
                }
        }
#pragma unroll
        for (int mt=0;mt<4;mt++){
            const int mq4 = wm + mt*16 + (quad<<2);
            f4v w0 = *(const f4v*)&wL[0][n][mq4];
            f4v w1 = *(const f4v*)&wL[1][n][mq4];
            f4v w2 = *(const f4v*)&wL[2][n][mq4];
#pragma unroll
            for (int rt=0;rt<2;rt++){
                accq[mt][rt] += w0 * cacc[mt][rt];
                acck[mt][rt] += w1 * cacc[mt][rt];
                accv[mt][rt] += w2 * cacc[mt][rt];
            }
        }
    }
#pragma unroll
    for (int mt=0;mt<4;mt++)
#pragma unroll
        for (int rt=0;rt<2;rt++){
            const int rcol = r0 + wr + rt*16 + l15;
#pragma unroll
            for (int e=0;e<4;e++){
                const int m = m0 + wm + mt*16 + (quad<<2) + e;
                const size_t idx = (size_t)m*Rr + rcol;
                qb[idx] = f2bf(accq[mt][rt][e]);
                kb[idx] = f2bf(acck[mt][rt][e]);
                vb[idx] = f2bf(accv[mt][rt][e]);
            }
        }
}

// ---------------- MFMA causal flash attention ----------------
__global__ __launch_bounds__(256) void k_attn_mfma(
    const u16* __restrict__ qb, const u16* __restrict__ kb, const u16* __restrict__ vtb,
    u16* __restrict__ ab)
{
    __shared__ __align__(16) u16 Ks[64*64];
    __shared__ __align__(16) u16 Vt[64*64];
    __shared__ __align__(16) u16 Ps[4*16*64];
    const int tid = threadIdx.x;
    const int lane = tid & 63, w = tid >> 6;
    const int quad = lane >> 4, l15 = lane & 15;
    const int bh = blockIdx.x;
    const int yq = blockIdx.y;
    const int qt = (yq < 16) ? yq : (47 - yq);
    const int b = bh >> 3, h = bh & 7;
    const u16* qbase = qb + (size_t)(b*Ss)*Rr + h*DHd;
    const u16* kbase = kb + (size_t)(b*Ss)*Rr + h*DHd;
    const u16* vtbase = vtb + (size_t)bh*DHd*Ss;
    s8v qf[2];
    {
        const size_t qrow = qt*64 + w*16 + l15;
        qf[0] = *(const s8v*)(qbase + qrow*Rr + quad*8);
        qf[1] = *(const s8v*)(qbase + qrow*Rr + 32 + quad*8);
    }
    const f4v fz = {0.f,0.f,0.f,0.f};
    f4v oacc[4];
#pragma unroll
    for (int dn=0;dn<4;dn++) oacc[dn]=fz;
    float m_e[4], l_e[4];
#pragma unroll
    for (int e=0;e<4;e++){ m_e[e] = -1e30f; l_e[e] = 0.f; }
    const int srow = lane>>3;
    const int sch  = (lane&7) ^ srow;
    u16* pw = Ps + w*1024;
    for (int kt=0; kt<=qt; kt++){
        __syncthreads();
        gld_lds16(kbase + (size_t)(kt*64 + w*8 + srow)*Rr + sch*8,        Ks + w*512);
        gld_lds16(kbase + (size_t)(kt*64 + 32 + w*8 + srow)*Rr + sch*8,   Ks + 2048 + w*512);
        gld_lds16(vtbase + (size_t)(w*8 + srow)*Ss + kt*64 + sch*8,       Vt + w*512);
        gld_lds16(vtbase + (size_t)(32 + w*8 + srow)*Ss + kt*64 + sch*8,  Vt + 2048 + w*512);
        __syncthreads();
        f4v s[4];
#pragma unroll
        for (int cn=0;cn<4;cn++) s[cn]=fz;
#pragma unroll
        for (int cn=0;cn<4;cn++)
#pragma unroll
            for (int kc=0;kc<2;kc++){
                s8v bf = *(const s8v*)(Ks + (cn*16 + l15)*64 + (((kc*4 + quad) ^ (l15&7))<<3));
                s[cn] = __builtin_amdgcn_mfma_f32_16x16x32_bf16(qf[kc], bf, s[cn], 0,0,0);
            }
        if (kt == qt){
            const int qg = qt*64 + w*16 + quad*4;
            const int kg = kt*64 + l15;
#pragma unroll
            for (int cn=0;cn<4;cn++)
#pragma unroll
                for (int e=0;e<4;e++){
                    float sv = s[cn][e]*0.125f;
                    s[cn][e] = ((kg + cn*16) > (qg + e)) ? -1e30f : sv;
                }
        } else {
#pragma unroll
            for (int cn=0;cn<4;cn++)
#pragma unroll
                for (int e=0;e<4;e++) s[cn][e] *= 0.125f;
        }
        float al_e[4];
#pragma unroll
        for (int e=0;e<4;e++){
            float mx = fmaxf(fmaxf(s[0][e],s[1][e]), fmaxf(s[2][e],s[3][e]));
#pragma unroll
            for (int off=1;off<16;off<<=1) mx = fmaxf(mx, __shfl_xor(mx, off));
            const float mt = fmaxf(m_e[e], mx);
            const float al = __expf(m_e[e] - mt);
            m_e[e] = mt;
            float sum = 0.f;
#pragma unroll
            for (int cn=0;cn<4;cn++){
                float p = __expf(s[cn][e] - mt);
                s[cn][e] = p; sum += p;
            }
#pragma unroll
            for (int off=1;off<16;off<<=1) sum += __shfl_xor(sum, off);
            l_e[e] = l_e[e]*al + sum;
            al_e[e] = al;
        }
#pragma unroll
        for (int e=0;e<4;e++){
            const int row = quad*4 + e;
#pragma unroll
            for (int cn=0;cn<4;cn++){
                const int key = cn*16 + l15;
                pw[row*64 + (((key>>3) ^ (row&7))<<3) + (key&7)] = f2bf(s[cn][e]);
            }
        }
#pragma unroll
        for (int dn=0;dn<4;dn++)
#pragma unroll
            for (int e=0;e<4;e++) oacc[dn][e] *= al_e[e];
#pragma unroll
        for (int dn=0;dn<4;dn++)
#pragma unroll
            for (int kc=0;kc<2;kc++){
                s8v pf = *(const s8v*)(pw + l15*64 + (((kc*4 + quad) ^ (l15&7))<<3));
                s8v vf = *(const s8v*)(Vt + (dn*16 + l15)*64 + (((kc*4 + quad) ^ (l15&7))<<3));
                oacc[dn] = __builtin_amdgcn_mfma_f32_16x16x32_bf16(pf, vf, oacc[dn], 0,0,0);
            }
    }
    u16* abase = ab + (size_t)(b*Ss + qt*64 + w*16)*Rr + h*DHd;
#pragma unroll
    for (int e=0;e<4;e++){
        const float inv = 1.f / l_e[e];
#pragma unroll
        for (int dn=0;dn<4;dn++)
            abase[(size_t)(quad*4+e)*Rr + dn*16 + l15] = f2bf(oacc[dn][e]*inv);
    }
}

// ---------------- output router softmax weights [M,8] (ab bf16, wro fp32) ----------------
__global__ __launch_bounds__(64) void k_router_o(
    const u16* __restrict__ ab, const float* __restrict__ wro, float* __restrict__ wo)
{
    const int m = blockIdx.x, lane = threadIdx.x;
    float a[8];
#pragma unroll
    for (int r=0;r<8;r++) a[r]=0.f;
#pragma unroll
    for (int i=0;i<2;i++){
        const size_t d0 = i*256 + lane*4;
        ushort4 av4 = *(const ushort4*)(ab + (size_t)m*Rr + d0);
        float a0=bf2f(av4.x), a1=bf2f(av4.y), a2=bf2f(av4.z), a3=bf2f(av4.w);
#pragma unroll
        for (int r=0;r<8;r++){
            float4 w4 = *(const float4*)(wro + (size_t)r*Rr + d0);
            a[r] += a0*w4.x + a1*w4.y + a2*w4.z + a3*w4.w;
        }
    }
#pragma unroll
    for (int r=0;r<8;r++)
#pragma unroll
        for (int off=32;off>=1;off>>=1) a[r]+=__shfl_xor(a[r],off);
    float mx=a[0];
#pragma unroll
    for (int r=1;r<8;r++) mx=fmaxf(mx,a[r]);
    float e[8], s=0.f;
#pragma unroll
    for (int r=0;r<8;r++){ e[r]=expf(a[r]-mx); s+=e[r]; }
    if (lane < 8) wo[m*8+lane] = e[lane]/s;
}

// ---------------- expand: out [M,D] fp32 via MFMA (BK=64, m-fast grid) ----------------
__global__ __launch_bounds__(256) void k_expand_mfma(
    const u16* __restrict__ ab, const u16* __restrict__ enT,
    const float* __restrict__ wo, float* __restrict__ out)
{
    __shared__ __align__(16) u16 As[128*64];
    __shared__ __align__(16) u16 Bs[64*64];
    __shared__ float wL[8][128];
    const int tid = threadIdx.x;
    const int lane = tid & 63, w = tid >> 6;
    const int quad = lane >> 4, l15 = lane & 15;
    const int m0 = blockIdx.x*128, dB0 = blockIdx.y*64;
    for (int i = tid; i < 8*128; i += 256){
        const int n = i >> 7, ml = i & 127;
        wL[n][ml] = wo[(size_t)(m0+ml)*8 + n];
    }
    const int wm = (w&1)*64, wr = (w>>1)*32;
    const int srow = lane>>3;
    const int sch  = (lane&7) ^ srow;
    f4v acc[4][2];
    const f4v fz = {0.f,0.f,0.f,0.f};
#pragma unroll
    for (int mt=0;mt<4;mt++)
#pragma unroll
        for (int rt=0;rt<2;rt++) acc[mt][rt]=fz;
    for (int n=0;n<8;n++){
        f4v cacc[4][2];
#pragma unroll
        for (int mt=0;mt<4;mt++)
#pragma unroll
            for (int rt=0;rt<2;rt++) cacc[mt][rt]=fz;
        const size_t bbase = (size_t)(n*1024 + dB0)*512;
        for (int s=0;s<8;s++){
            const int r0k = s*64;
            __syncthreads();
#pragma unroll
            for (int i=0;i<4;i++)
                gld_lds16(ab + (size_t)(m0 + i*32 + w*8 + srow)*Rr + r0k + sch*8,
                          As + (i*32 + w*8)*64);
#pragma unroll
            for (int i=0;i<2;i++)
                gld_lds16(enT + bbase + (size_t)(i*32 + w*8 + srow)*512 + r0k + sch*8,
                          Bs + (i*32 + w*8)*64);
            __syncthreads();
            s8v af[4][2], bf[2][2];
#pragma unroll
            for (int mt=0;mt<4;mt++)
#pragma unroll
                for (int kc=0;kc<2;kc++)
                    af[mt][kc] = *(const s8v*)(As + (wm + mt*16 + l15)*64 + (((kc*4+quad) ^ (l15&7))<<3));
#pragma unroll
            for (int rt=0;rt<2;rt++)
#pragma unroll
                for (int kc=0;kc<2;kc++)
                    bf[rt][kc] = *(const s8v*)(Bs + (wr + rt*16 + l15)*64 + (((kc*4+quad) ^ (l15&7))<<3));
#pragma unroll
            for (int mt=0;mt<4;mt++)
#pragma unroll
                for (int rt=0;rt<2;rt++){
                    cacc[mt][rt] = __builtin_amdgcn_mfma_f32_16x16x32_bf16(af[mt][0], bf[rt][0], cacc[mt][rt], 0,0,0);
                    cacc[mt][rt] = __builtin_amdgcn_mfma_f32_16x16x32_bf16(af[mt][1], bf[rt][1], cacc[mt][rt], 0,0,0);
                }
        }
#pragma unroll
        for (int mt=0;mt<4;mt++){
            const int mq4 = wm + mt*16 + (quad<<2);
            f4v w0 = *(const f4v*)&wL[n][mq4];
#pragma unroll
            for (int rt=0;rt<2;rt++) acc[mt][rt] += w0 * cacc[mt][rt];
        }
    }
#pragma unroll
    for (int mt=0;mt<4;mt++)
#pragma unroll
        for (int rt=0;rt<2;rt++){
            const int dcol = dB0 + wr + rt*16 + l15;
#pragma unroll
            for (int e=0;e<4;e++){
                const int m = m0 + wm + mt*16 + (quad<<2) + e;
                out[(size_t)m*Dd + dcol] = acc[mt][rt][e];   // fp32 output
            }
        }
}

extern "C" void kernel_launch(void* const* d_in, const int* in_sizes, int n_in,
                              void* d_out, int out_size, void* d_ws, size_t ws_size,
                              hipStream_t stream) {
    (void)in_sizes; (void)n_in; (void)out_size; (void)ws_size;
    const float* x   = (const float*)d_in[0];
    // d_in[1] = causal mask — deterministic, unused
    const float* cn  = (const float*)d_in[2];
    const float* en  = (const float*)d_in[3];
    const float* wrq = (const float*)d_in[4];
    const float* wrk = (const float*)d_in[5];
    const float* wrv = (const float*)d_in[6];
    const float* wro = (const float*)d_in[7];

    float* ws = (float*)d_ws;
    float* wq = ws;                          // [M,8] f32
    float* wk = wq + Mm*8;
    float* wv = wk + Mm*8;
    float* wo = wv + Mm*8;
    u16* xb  = (u16*)(wo + Mm*8);            // [M,D] bf16
    u16* qb  = xb + (size_t)Mm*Dd;           // [M,R] bf16
    u16* kb  = qb + (size_t)Mm*Rr;
    u16* vb  = kb + (size_t)Mm*Rr;
    u16* ab  = vb + (size_t)Mm*Rr;           // attention out [M,R] bf16
    u16* cnT = ab + (size_t)Mm*Rr;           // [8][R][D] bf16
    u16* enT = cnT + (size_t)8*Rr*Dd;        // [8][D][R] bf16
    u16* vtb = enT + (size_t)8*Dd*Rr;        // [BH][DH][S] bf16

    k_f2b<<<Mm*Dd/1024, 256, 0, stream>>>(x, xb);
    k_transpose_f2b<<<dim3(Dd/64, Rr/64, 8), 256, 0, stream>>>(cn, cnT, Dd, Rr);
    k_transpose_f2b<<<dim3(Rr/64, Dd/64, 8), 256, 0, stream>>>(en, enT, Rr, Dd);
    k_router_qkv<<<Mm, 64, 0, stream>>>(x, wrq, wrk, wrv, wq, wk, wv);
    // m-fastest grid: same-m blocks land on the same XCD (id % 8 == m % 8)
    k_compress_mfma<<<dim3(Mm/128, Rr/64), 256, 0, stream>>>(xb, cnT, wq, wk, wv, qb, kb, vb);
    k_transpose_v<<<dim3(Ss/64, Bb*Hh), 256, 0, stream>>>(vb, vtb);
    k_attn_mfma<<<dim3(Bb*Hh, Ss/64), 256, 0, stream>>>(qb, kb, vtb, ab);
    k_router_o<<<Mm, 64, 0, stream>>>(ab, wro, wo);
    k_expand_mfma<<<dim3(Mm/128, Dd/64), 256, 0, stream>>>(ab, enT, wo, (float*)d_out);
}